// Round 6
// baseline (100.094 us; speedup 1.0000x reference)
//
#include <hip/hip_runtime.h>
#include <hip/hip_bf16.h>
#include <cstddef>

#define T_DIM 2048
#define D_DIM 1024
#define GAMMA_F 0.96875f

typedef __attribute__((ext_vector_type(8))) short bf16x8;
typedef __attribute__((ext_vector_type(8))) ushort ushortx8;
typedef __attribute__((ext_vector_type(4))) float f32x4;

#define AS1 __attribute__((address_space(1)))
#define AS3 __attribute__((address_space(3)))

static __device__ inline ushort f2bs(float f) {
    __hip_bfloat16 h = __float2bfloat16(f);
    return *reinterpret_cast<ushort*>(&h);
}

// ---------------------------------------------------------------------------
// K0: wv_sum[i] = sum_d Wv[i][d]
// ---------------------------------------------------------------------------
__global__ __launch_bounds__(256) void k_wvsum(const float* __restrict__ Wv,
                                               float* __restrict__ wv_sum) {
    __shared__ float red[4];
    const int i = blockIdx.x;
    const int tid = threadIdx.x;
    const float* row = Wv + (size_t)i * D_DIM;
    float p = 0.f;
    for (int c = tid; c < D_DIM; c += 256) p += row[c];
    for (int o = 32; o; o >>= 1) p += __shfl_down(p, o);
    if ((tid & 63) == 0) red[tid >> 6] = p;
    __syncthreads();
    if (tid == 0) wv_sum[i] = red[0] + red[1] + red[2] + red[3];
}

// ---------------------------------------------------------------------------
// K1: per t: vsum[b] = x[b,t,:].wv_sum;  y[t,i] = sum_b x[b,t,i]*vsum[b]
// Emits bf16 ROW-MAJOR: yb [T,D], xb [B*T,D]. Vectorized loads/stores.
// ---------------------------------------------------------------------------
__global__ __launch_bounds__(256) void k_vsum_y(const float* __restrict__ x,
                                                const float* __restrict__ wv_sum,
                                                ushort* __restrict__ yb,
                                                ushort* __restrict__ xb) {
    __shared__ float xs[4][D_DIM];
    __shared__ float red[4][4];   // [wave][b]
    const int t = blockIdx.x;
    const int tid = threadIdx.x;
    const int lane = tid & 63, wv = tid >> 6;

    #pragma unroll
    for (int b = 0; b < 4; ++b) {
        const float4* xr = (const float4*)(x + ((size_t)b * T_DIM + t) * D_DIM);
        *(float4*)&xs[b][tid * 4] = xr[tid];
    }
    __syncthreads();

    #pragma unroll
    for (int b = 0; b < 4; ++b) {
        float p = 0.f;
        for (int c = tid; c < D_DIM; c += 256) p += xs[b][c] * wv_sum[c];
        for (int o = 32; o; o >>= 1) p += __shfl_down(p, o);
        if (lane == 0) red[wv][b] = p;
    }
    __syncthreads();

    float vs[4];
    #pragma unroll
    for (int b = 0; b < 4; ++b)
        vs[b] = red[0][b] + red[1][b] + red[2][b] + red[3][b];

    if (tid < 128) {                       // y row t: 128 groups of 8
        const int i0 = tid * 8;
        ushortx8 yv;
        #pragma unroll
        for (int j = 0; j < 8; ++j) {
            float a = 0.f;
            #pragma unroll
            for (int b = 0; b < 4; ++b) a += xs[b][i0 + j] * vs[b];
            yv[j] = f2bs(a);
        }
        *(ushortx8*)(yb + (size_t)t * D_DIM + i0) = yv;
    }
    for (int g = tid; g < 512; g += 256) { // xb rows b*T+t
        const int b = g >> 7, i0 = (g & 127) * 8;
        ushortx8 xv;
        #pragma unroll
        for (int j = 0; j < 8; ++j) xv[j] = f2bs(xs[b][i0 + j]);
        *(ushortx8*)(xb + ((size_t)b * T_DIM + t) * D_DIM + i0) = xv;
    }
}

// ---------------------------------------------------------------------------
// K2: W [K=1024][N=1024] fp32 -> BT [N][K] bf16 (row-major transpose)
// ---------------------------------------------------------------------------
__global__ __launch_bounds__(256) void k_cvtWT(const float* __restrict__ W,
                                               ushort* __restrict__ WT) {
    __shared__ float tile[32][33];          // [k][n]
    const int tx = threadIdx.x & 31, ty = threadIdx.x >> 5;  // 32 x 8
    const int kb = blockIdx.x * 32, nb = blockIdx.y * 32;
    #pragma unroll
    for (int r = 0; r < 4; ++r)
        tile[ty + 8 * r][tx] = W[(size_t)(kb + ty + 8 * r) * 1024 + nb + tx];
    __syncthreads();
    #pragma unroll
    for (int r = 0; r < 4; ++r)
        WT[(size_t)(nb + ty + 8 * r) * 1024 + kb + tx] =
            f2bs(tile[tx][ty + 8 * r]);
}

// ---------------------------------------------------------------------------
// K3: bf16 MFMA GEMM  C[M,1024] = A[M,1024] @ B[1024,1024]
// A [M,K] bf16 row-major; BT [N,K] bf16. Tile (MF*32) x (NF*32), BK=64,
// 4 waves (2x2), per-wave (MF*16) x (NF*16) frags of 16x16x32.
// DOUBLE-BUFFERED LDS (T3-minimum): stage K-tile kt+1 into buf^1 BEFORE
// ds_read+MFMA of buf, then ONE __syncthreads per K-tile (its implicit
// vmcnt(0)+lgkmcnt(0) drain lands after the MFMA cluster, so global-load
// latency overlaps compute). 128B LDS rows -> XOR swizzle both sides
// (inverse-swizzled global source keeps gload_lds dest linear, rule #21).
// EPI=1 fuses out[r,d] = acc * S[2d + (t>>10)][t&1023], t = r & 2047.
// ---------------------------------------------------------------------------
template <int MF, int NF, int EPI>
__global__ __launch_bounds__(256) void k_gemm(const ushort* __restrict__ A,
                                              const ushort* __restrict__ BT,
                                              float* __restrict__ C,
                                              const float* __restrict__ S) {
    constexpr int BM = MF * 32;
    constexpr int BN = NF * 32;
    __shared__ ushort As[2][BM][64];       // 2 x BM*128 bytes
    __shared__ ushort Bs[2][BN][64];
    const int tid = threadIdx.x;
    const int lane = tid & 63, wid = tid >> 6;
    const int wr = wid >> 1, wc = wid & 1;
    const int rowBase = blockIdx.x * BM;
    const int colBase = blockIdx.y * BN;

    f32x4 acc[MF][NF];
    #pragma unroll
    for (int i = 0; i < MF; ++i)
        #pragma unroll
        for (int j = 0; j < NF; ++j) acc[i][j] = f32x4{0.f, 0.f, 0.f, 0.f};

    auto stage = [&](int buf, int kb) {
        #pragma unroll
        for (int q = 0; q < BM / 32; ++q) {
            const int s = q * 4096 + tid * 16;           // linear LDS byte
            const int r = s >> 7, grp = (s >> 4) & 7;
            const int gcol = kb + (((grp ^ (r & 7)) & 7) << 3);
            __builtin_amdgcn_global_load_lds(
                (const AS1 void*)(A + (size_t)(rowBase + r) * 1024 + gcol),
                (AS3 void*)((AS3 char*)&As[buf][0][0] + s), 16, 0, 0);
        }
        #pragma unroll
        for (int q = 0; q < BN / 32; ++q) {
            const int s = q * 4096 + tid * 16;
            const int r = s >> 7, grp = (s >> 4) & 7;
            const int gcol = kb + (((grp ^ (r & 7)) & 7) << 3);
            __builtin_amdgcn_global_load_lds(
                (const AS1 void*)(BT + (size_t)(colBase + r) * 1024 + gcol),
                (AS3 void*)((AS3 char*)&Bs[buf][0][0] + s), 16, 0, 0);
        }
    };

    stage(0, 0);
    __syncthreads();                        // drains vmcnt(0): buf0 ready

    #pragma unroll 2
    for (int kt = 0; kt < 16; ++kt) {
        const int cur = kt & 1;
        if (kt < 15) stage(cur ^ 1, (kt + 1) * 64);   // prefetch next K-tile

        bf16x8 af[2][MF], bfv[2][NF];
        #pragma unroll
        for (int ks = 0; ks < 2; ++ks) {
            const int kg = ks * 4 + (lane >> 4);
            #pragma unroll
            for (int mi = 0; mi < MF; ++mi) {
                const int r = wr * (MF * 16) + mi * 16 + (lane & 15);
                af[ks][mi] = *(const bf16x8*)((const char*)&As[cur][0][0] +
                                              r * 128 + (((kg ^ (r & 7)) & 7) << 4));
            }
            #pragma unroll
            for (int ni = 0; ni < NF; ++ni) {
                const int r = wc * (NF * 16) + ni * 16 + (lane & 15);
                bfv[ks][ni] = *(const bf16x8*)((const char*)&Bs[cur][0][0] +
                                               r * 128 + (((kg ^ (r & 7)) & 7) << 4));
            }
        }
        #pragma unroll
        for (int ks = 0; ks < 2; ++ks)
            #pragma unroll
            for (int mi = 0; mi < MF; ++mi)
                #pragma unroll
                for (int ni = 0; ni < NF; ++ni)
                    acc[mi][ni] = __builtin_amdgcn_mfma_f32_16x16x32_bf16(
                        af[ks][mi], bfv[ks][ni], acc[mi][ni], 0, 0, 0);

        if (kt < 15) __syncthreads();       // next buffer staged; all reads done
    }

    #pragma unroll
    for (int mi = 0; mi < MF; ++mi) {
        #pragma unroll
        for (int ni = 0; ni < NF; ++ni) {
            const int col = colBase + wc * (NF * 16) + ni * 16 + (lane & 15);
            #pragma unroll
            for (int q = 0; q < 4; ++q) {
                const int row = rowBase + wr * (MF * 16) + mi * 16 + (lane >> 4) * 4 + q;
                float v = acc[mi][ni][q];
                if (EPI) {
                    const int t = row & (T_DIM - 1);
                    v *= S[(size_t)(2 * col + (t >> 10)) * D_DIM + (t & 1023)];
                }
                C[(size_t)row * D_DIM + col] = v;
            }
        }
    }
}

// ---------------------------------------------------------------------------
// Parallel scan over t: S[t] = g*S[t-1] + m[t], m[0]:=0, then S[0]=S[1].
// 64 chunks of 32 per column.
// ---------------------------------------------------------------------------
#define SC_L 32
#define SC_NC 64

__global__ __launch_bounds__(256) void k_scan1(const float* __restrict__ m,
                                               float* __restrict__ tot) {
    const int col = blockIdx.x * 64 + (threadIdx.x & 63);
    const int ch  = blockIdx.y * 4 + (threadIdx.x >> 6);
    const int t0 = ch * SC_L;
    float r = 0.f;
    #pragma unroll 4
    for (int k = 0; k < SC_L; ++k) {
        const int t = t0 + k;
        const float a = (t == 0) ? 0.f : m[(size_t)t * D_DIM + col];
        r = GAMMA_F * r + a;
    }
    tot[(size_t)ch * D_DIM + col] = r;
}

__global__ __launch_bounds__(256) void k_scan2(float* __restrict__ m,
                                               const float* __restrict__ tot) {
    const int col = blockIdx.x * 64 + (threadIdx.x & 63);
    const int ch  = blockIdx.y * 4 + (threadIdx.x >> 6);
    const int t0 = ch * SC_L;

    float gL = 1.f;
    #pragma unroll
    for (int i = 0; i < SC_L; ++i) gL *= GAMMA_F;

    float carry = 0.f, f = 1.f;    // carry = sum_{j<ch} (g^L)^(ch-1-j) tot[j]
    for (int j = ch - 1; j >= 0; --j) {
        carry += f * tot[(size_t)j * D_DIM + col];
        f *= gL;
    }

    float r = carry, s1 = 0.f;
    #pragma unroll 4
    for (int k = 0; k < SC_L; ++k) {
        const int t = t0 + k;
        const float a = (t == 0) ? 0.f : m[(size_t)t * D_DIM + col];
        r = GAMMA_F * r + a;
        m[(size_t)t * D_DIM + col] = r;
        if (t == 1) s1 = r;
    }
    if (ch == 0) m[col] = s1;      // S[0] = S[1]
}

// ---------------------------------------------------------------------------
extern "C" void kernel_launch(void* const* d_in, const int* in_sizes, int n_in,
                              void* d_out, int out_size, void* d_ws, size_t ws_size,
                              hipStream_t stream) {
    const float* x  = (const float*)d_in[0];   // [4,2048,1024]
    const float* Wq = (const float*)d_in[1];
    const float* Wk = (const float*)d_in[2];
    const float* Wv = (const float*)d_in[3];
    float* out = (float*)d_out;                // [4,2048,1024] fp32
    char* ws = (char*)d_ws;

    // ws layout, 30 MB total (proven available):
    ushort* xb  = (ushort*)(ws);                    // 16 MB  [B*T,D] bf16
    float*  m   = (float*)(ws + (16u << 20));       //  8 MB  [T,D] fp32
    ushort* yb  = (ushort*)(ws + (24u << 20));      //  4 MB  [T,D] bf16
    ushort* WT  = (ushort*)(ws + (28u << 20));      //  2 MB  BT (Wk then Wq)
    float*  wv_sum = m;                 // m row 0: free until gemm<0> writes it
    float*  tot = (float*)yb;           // yb consumed by gemm<0> before scans

    k_wvsum<<<D_DIM, 256, 0, stream>>>(Wv, wv_sum);
    k_vsum_y<<<T_DIM, 256, 0, stream>>>(x, wv_sum, (ushort*)yb, (ushort*)xb);

    dim3 gW(32, 32);
    k_cvtWT<<<gW, 256, 0, stream>>>(Wk, WT);

    // m = y @ Wk : tile 64x64, grid (32,16) = 512 blocks (2/CU, 8 waves/CU)
    dim3 gm(T_DIM / 64, D_DIM / 64);
    k_gemm<2, 2, 0><<<gm, 256, 0, stream>>>(yb, WT, m, nullptr);

    dim3 gs(D_DIM / 64, SC_NC / 4);
    k_scan1<<<gs, 256, 0, stream>>>(m, tot);
    k_scan2<<<gs, 256, 0, stream>>>(m, tot);

    k_cvtWT<<<gW, 256, 0, stream>>>(Wq, WT);   // reuse after gemm<0> done

    // out = (S-scramble) * (x @ Wq) : tile 128x128, grid (64,8) = 512 blocks
    dim3 gq((4 * T_DIM) / 128, D_DIM / 128);
    k_gemm<4, 4, 1><<<gq, 256, 0, stream>>>(xb, WT, out, m);
}

// Round 7
// 90.080 us; speedup vs baseline: 1.1112x; 1.1112x over previous
//
#include <hip/hip_runtime.h>
#include <hip/hip_bf16.h>
#include <cstddef>

#define T_DIM 2048
#define D_DIM 1024
#define GAMMA_F 0.96875f

typedef __attribute__((ext_vector_type(8))) short bf16x8;
typedef __attribute__((ext_vector_type(8))) ushort ushortx8;
typedef __attribute__((ext_vector_type(4))) float f32x4;

#define AS1 __attribute__((address_space(1)))
#define AS3 __attribute__((address_space(3)))

static __device__ inline ushort f2bs(float f) {
    __hip_bfloat16 h = __float2bfloat16(f);
    return *reinterpret_cast<ushort*>(&h);
}

template <int N>
static __device__ __forceinline__ void vm_wait() {
    if constexpr (N == 0)      asm volatile("s_waitcnt vmcnt(0)" ::: "memory");
    else if constexpr (N == 4) asm volatile("s_waitcnt vmcnt(4)" ::: "memory");
    else if constexpr (N == 8) asm volatile("s_waitcnt vmcnt(8)" ::: "memory");
    else                       static_assert(N == 0 || N == 4 || N == 8, "vmcnt");
}
static __device__ __forceinline__ void raw_barrier() {
    asm volatile("s_barrier" ::: "memory");
}

// ---------------------------------------------------------------------------
// K_prep: z=0: Wk -> WTk [N][K] bf16; z=1: Wq -> WTq; z=2: wv_sum[i]=sum Wv[i][:]
// ---------------------------------------------------------------------------
__global__ __launch_bounds__(256) void k_prep(const float* __restrict__ Wk,
                                              const float* __restrict__ Wq,
                                              const float* __restrict__ Wv,
                                              ushort* __restrict__ WTk,
                                              ushort* __restrict__ WTq,
                                              float* __restrict__ wv_sum) {
    const int tid = threadIdx.x;
    if (blockIdx.z == 2) {
        __shared__ float red[4];
        const int i = blockIdx.y * 32 + blockIdx.x;
        const float* row = Wv + (size_t)i * D_DIM;
        float p = 0.f;
        for (int c = tid; c < D_DIM; c += 256) p += row[c];
        for (int o = 32; o; o >>= 1) p += __shfl_down(p, o);
        if ((tid & 63) == 0) red[tid >> 6] = p;
        __syncthreads();
        if (tid == 0) wv_sum[i] = red[0] + red[1] + red[2] + red[3];
        return;
    }
    const float* W = (blockIdx.z == 0) ? Wk : Wq;
    ushort* WT     = (blockIdx.z == 0) ? WTk : WTq;
    __shared__ float tile[32][33];          // [k][n]
    const int tx = tid & 31, ty = tid >> 5; // 32 x 8
    const int kb = blockIdx.x * 32, nb = blockIdx.y * 32;
    #pragma unroll
    for (int r = 0; r < 4; ++r)
        tile[ty + 8 * r][tx] = W[(size_t)(kb + ty + 8 * r) * 1024 + nb + tx];
    __syncthreads();
    #pragma unroll
    for (int r = 0; r < 4; ++r)
        WT[(size_t)(nb + ty + 8 * r) * 1024 + kb + tx] =
            f2bs(tile[tx][ty + 8 * r]);
}

// ---------------------------------------------------------------------------
// K1: per t: vsum[b] = x[b,t,:].wv_sum;  y[t,i] = sum_b x[b,t,i]*vsum[b]
// Emits bf16 ROW-MAJOR: yb [T,D], xb [B*T,D]. Vectorized loads/stores.
// ---------------------------------------------------------------------------
__global__ __launch_bounds__(256) void k_vsum_y(const float* __restrict__ x,
                                                const float* __restrict__ wv_sum,
                                                ushort* __restrict__ yb,
                                                ushort* __restrict__ xb) {
    __shared__ float xs[4][D_DIM];
    __shared__ float red[4][4];   // [wave][b]
    const int t = blockIdx.x;
    const int tid = threadIdx.x;
    const int lane = tid & 63, wv = tid >> 6;

    #pragma unroll
    for (int b = 0; b < 4; ++b) {
        const float4* xr = (const float4*)(x + ((size_t)b * T_DIM + t) * D_DIM);
        *(float4*)&xs[b][tid * 4] = xr[tid];
    }
    __syncthreads();

    #pragma unroll
    for (int b = 0; b < 4; ++b) {
        float p = 0.f;
        for (int c = tid; c < D_DIM; c += 256) p += xs[b][c] * wv_sum[c];
        for (int o = 32; o; o >>= 1) p += __shfl_down(p, o);
        if (lane == 0) red[wv][b] = p;
    }
    __syncthreads();

    float vs[4];
    #pragma unroll
    for (int b = 0; b < 4; ++b)
        vs[b] = red[0][b] + red[1][b] + red[2][b] + red[3][b];

    if (tid < 128) {                       // y row t: 128 groups of 8
        const int i0 = tid * 8;
        ushortx8 yv;
        #pragma unroll
        for (int j = 0; j < 8; ++j) {
            float a = 0.f;
            #pragma unroll
            for (int b = 0; b < 4; ++b) a += xs[b][i0 + j] * vs[b];
            yv[j] = f2bs(a);
        }
        *(ushortx8*)(yb + (size_t)t * D_DIM + i0) = yv;
    }
    for (int g = tid; g < 512; g += 256) { // xb rows b*T+t
        const int b = g >> 7, i0 = (g & 127) * 8;
        ushortx8 xv;
        #pragma unroll
        for (int j = 0; j < 8; ++j) xv[j] = f2bs(xs[b][i0 + j]);
        *(ushortx8*)(xb + ((size_t)b * T_DIM + t) * D_DIM + i0) = xv;
    }
}

// ---------------------------------------------------------------------------
// K3: bf16 MFMA GEMM  C[M,1024] = A[M,1024] @ B[1024,1024]
// A [M,K] bf16 row-major; BT [N,K] bf16. Tile (MF*32) x (NF*32), BK=64,
// 4 waves (2x2). Double-buffered LDS with COUNTED vmcnt (T3+T4 minimum):
//   per iter: stage(next buf) ; s_waitcnt vmcnt(LOADS) [prev tile ready,
//   next tile's loads stay IN FLIGHT across both barriers] ; s_barrier ;
//   ds_read cur ; MFMA ; lgkmcnt(0) ; s_barrier.
// Never vmcnt(0) in the main loop (m218: counted-vs-drain0 = +38-73%).
// 128B LDS rows -> XOR swizzle both sides (inverse-swizzled global source,
// linear gload_lds dest, swizzled ds_read — rule #21).
// EPI=1 fuses out[r,d] = acc * S[2d + (t>>10)][t&1023], t = r & 2047.
// ---------------------------------------------------------------------------
template <int MF, int NF, int EPI>
__global__ __launch_bounds__(256) void k_gemm(const ushort* __restrict__ A,
                                              const ushort* __restrict__ BT,
                                              float* __restrict__ C,
                                              const float* __restrict__ S) {
    constexpr int BM = MF * 32;
    constexpr int BN = NF * 32;
    constexpr int LOADS = BM / 32 + BN / 32;   // gload_lds per thread per stage
    __shared__ ushort As[2][BM][64];
    __shared__ ushort Bs[2][BN][64];
    const int tid = threadIdx.x;
    const int lane = tid & 63, wid = tid >> 6;
    const int wr = wid >> 1, wc = wid & 1;
    const int rowBase = blockIdx.x * BM;
    const int colBase = blockIdx.y * BN;

    f32x4 acc[MF][NF];
    #pragma unroll
    for (int i = 0; i < MF; ++i)
        #pragma unroll
        for (int j = 0; j < NF; ++j) acc[i][j] = f32x4{0.f, 0.f, 0.f, 0.f};

    auto stage = [&](int buf, int kb) {
        #pragma unroll
        for (int q = 0; q < BM / 32; ++q) {
            const int s = q * 4096 + tid * 16;           // linear LDS byte
            const int r = s >> 7, grp = (s >> 4) & 7;
            const int gcol = kb + (((grp ^ (r & 7)) & 7) << 3);
            __builtin_amdgcn_global_load_lds(
                (const AS1 void*)(A + (size_t)(rowBase + r) * 1024 + gcol),
                (AS3 void*)((AS3 char*)&As[buf][0][0] + s), 16, 0, 0);
        }
        #pragma unroll
        for (int q = 0; q < BN / 32; ++q) {
            const int s = q * 4096 + tid * 16;
            const int r = s >> 7, grp = (s >> 4) & 7;
            const int gcol = kb + (((grp ^ (r & 7)) & 7) << 3);
            __builtin_amdgcn_global_load_lds(
                (const AS1 void*)(BT + (size_t)(colBase + r) * 1024 + gcol),
                (AS3 void*)((AS3 char*)&Bs[buf][0][0] + s), 16, 0, 0);
        }
    };

    stage(0, 0);                           // in flight; waited inside iter 0

    #pragma unroll 2
    for (int kt = 0; kt < 16; ++kt) {
        const int cur = kt & 1;
        if (kt < 15) {
            stage(cur ^ 1, (kt + 1) * 64); // next tile's loads join the queue
            vm_wait<LOADS>();              // wait ONLY for tile kt's loads
        } else {
            vm_wait<0>();
        }
        raw_barrier();                     // buf[cur] valid for all waves

        bf16x8 af[2][MF], bfv[2][NF];
        #pragma unroll
        for (int ks = 0; ks < 2; ++ks) {
            const int kg = ks * 4 + (lane >> 4);
            #pragma unroll
            for (int mi = 0; mi < MF; ++mi) {
                const int r = wr * (MF * 16) + mi * 16 + (lane & 15);
                af[ks][mi] = *(const bf16x8*)((const char*)&As[cur][0][0] +
                                              r * 128 + (((kg ^ (r & 7)) & 7) << 4));
            }
            #pragma unroll
            for (int ni = 0; ni < NF; ++ni) {
                const int r = wc * (NF * 16) + ni * 16 + (lane & 15);
                bfv[ks][ni] = *(const bf16x8*)((const char*)&Bs[cur][0][0] +
                                               r * 128 + (((kg ^ (r & 7)) & 7) << 4));
            }
        }
        #pragma unroll
        for (int ks = 0; ks < 2; ++ks)
            #pragma unroll
            for (int mi = 0; mi < MF; ++mi)
                #pragma unroll
                for (int ni = 0; ni < NF; ++ni)
                    acc[mi][ni] = __builtin_amdgcn_mfma_f32_16x16x32_bf16(
                        af[ks][mi], bfv[ks][ni], acc[mi][ni], 0, 0, 0);

        asm volatile("s_waitcnt lgkmcnt(0)" ::: "memory");
        raw_barrier();                     // all reads done; next stage may overwrite
    }

    #pragma unroll
    for (int mi = 0; mi < MF; ++mi) {
        #pragma unroll
        for (int ni = 0; ni < NF; ++ni) {
            const int col = colBase + wc * (NF * 16) + ni * 16 + (lane & 15);
            #pragma unroll
            for (int q = 0; q < 4; ++q) {
                const int row = rowBase + wr * (MF * 16) + mi * 16 + (lane >> 4) * 4 + q;
                float v = acc[mi][ni][q];
                if (EPI) {
                    const int t = row & (T_DIM - 1);
                    v *= S[(size_t)(2 * col + (t >> 10)) * D_DIM + (t & 1023)];
                }
                C[(size_t)row * D_DIM + col] = v;
            }
        }
    }
}

// ---------------------------------------------------------------------------
// Parallel scan over t: S[t] = g*S[t-1] + m[t], m[0]:=0, then S[0]=S[1].
// 64 chunks of 32 per column.
// ---------------------------------------------------------------------------
#define SC_L 32
#define SC_NC 64

__global__ __launch_bounds__(256) void k_scan1(const float* __restrict__ m,
                                               float* __restrict__ tot) {
    const int col = blockIdx.x * 64 + (threadIdx.x & 63);
    const int ch  = blockIdx.y * 4 + (threadIdx.x >> 6);
    const int t0 = ch * SC_L;
    float r = 0.f;
    #pragma unroll 4
    for (int k = 0; k < SC_L; ++k) {
        const int t = t0 + k;
        const float a = (t == 0) ? 0.f : m[(size_t)t * D_DIM + col];
        r = GAMMA_F * r + a;
    }
    tot[(size_t)ch * D_DIM + col] = r;
}

__global__ __launch_bounds__(256) void k_scan2(float* __restrict__ m,
                                               const float* __restrict__ tot) {
    const int col = blockIdx.x * 64 + (threadIdx.x & 63);
    const int ch  = blockIdx.y * 4 + (threadIdx.x >> 6);
    const int t0 = ch * SC_L;

    float gL = 1.f;
    #pragma unroll
    for (int i = 0; i < SC_L; ++i) gL *= GAMMA_F;

    float carry = 0.f, f = 1.f;    // carry = sum_{j<ch} (g^L)^(ch-1-j) tot[j]
    for (int j = ch - 1; j >= 0; --j) {
        carry += f * tot[(size_t)j * D_DIM + col];
        f *= gL;
    }

    float r = carry, s1 = 0.f;
    #pragma unroll 4
    for (int k = 0; k < SC_L; ++k) {
        const int t = t0 + k;
        const float a = (t == 0) ? 0.f : m[(size_t)t * D_DIM + col];
        r = GAMMA_F * r + a;
        m[(size_t)t * D_DIM + col] = r;
        if (t == 1) s1 = r;
    }
    if (ch == 0) m[col] = s1;      // S[0] = S[1]
}

// ---------------------------------------------------------------------------
extern "C" void kernel_launch(void* const* d_in, const int* in_sizes, int n_in,
                              void* d_out, int out_size, void* d_ws, size_t ws_size,
                              hipStream_t stream) {
    const float* x  = (const float*)d_in[0];   // [4,2048,1024]
    const float* Wq = (const float*)d_in[1];
    const float* Wk = (const float*)d_in[2];
    const float* Wv = (const float*)d_in[3];
    float* out = (float*)d_out;                // [4,2048,1024] fp32
    char* ws = (char*)d_ws;

    // ws layout (32 MB; ws is 256 MiB per harness poison trace):
    ushort* xb  = (ushort*)(ws);                    // 16 MB  [B*T,D] bf16
    float*  m   = (float*)(ws + (16u << 20));       //  8 MB  [T,D] fp32
    ushort* yb  = (ushort*)(ws + (24u << 20));      //  4 MB  [T,D] bf16
    ushort* WTk = (ushort*)(ws + (28u << 20));      //  2 MB
    ushort* WTq = (ushort*)(ws + (30u << 20));      //  2 MB
    float*  wv_sum = m;                 // m row 0: free until gemm<0> writes it
    float*  tot = (float*)yb;           // yb consumed by gemm<0> before scans

    dim3 gP(32, 32, 3);
    k_prep<<<gP, 256, 0, stream>>>(Wk, Wq, Wv, WTk, WTq, wv_sum);

    k_vsum_y<<<T_DIM, 256, 0, stream>>>(x, wv_sum, (ushort*)yb, (ushort*)xb);

    // m = y @ Wk : tile 64x64, grid (32,16) = 512 blocks
    dim3 gm(T_DIM / 64, D_DIM / 64);
    k_gemm<2, 2, 0><<<gm, 256, 0, stream>>>(yb, WTk, m, nullptr);

    dim3 gs(D_DIM / 64, SC_NC / 4);
    k_scan1<<<gs, 256, 0, stream>>>(m, tot);
    k_scan2<<<gs, 256, 0, stream>>>(m, tot);

    // out = (S-scramble) * (x @ Wq) : tile 128x128, grid (64,8) = 512 blocks
    dim3 gq((4 * T_DIM) / 128, D_DIM / 128);
    k_gemm<4, 4, 1><<<gq, 256, 0, stream>>>(xb, WTq, out, m);
}

// Round 8
// 80.322 us; speedup vs baseline: 1.2462x; 1.1215x over previous
//
#include <hip/hip_runtime.h>
#include <hip/hip_bf16.h>
#include <cstddef>

#define T_DIM 2048
#define D_DIM 1024
#define GAMMA_F 0.96875f

typedef __attribute__((ext_vector_type(8))) short bf16x8;
typedef __attribute__((ext_vector_type(8))) ushort ushortx8;
typedef __attribute__((ext_vector_type(4))) float f32x4;

#define AS1 __attribute__((address_space(1)))
#define AS3 __attribute__((address_space(3)))

static __device__ inline ushort f2bs(float f) {
    __hip_bfloat16 h = __float2bfloat16(f);
    return *reinterpret_cast<ushort*>(&h);
}

template <int N>
static __device__ __forceinline__ void vm_wait() {
    if constexpr (N == 0)      asm volatile("s_waitcnt vmcnt(0)" ::: "memory");
    else if constexpr (N == 2) asm volatile("s_waitcnt vmcnt(2)" ::: "memory");
    else if constexpr (N == 3) asm volatile("s_waitcnt vmcnt(3)" ::: "memory");
    else if constexpr (N == 4) asm volatile("s_waitcnt vmcnt(4)" ::: "memory");
    else if constexpr (N == 6) asm volatile("s_waitcnt vmcnt(6)" ::: "memory");
    else if constexpr (N == 8) asm volatile("s_waitcnt vmcnt(8)" ::: "memory");
    else static_assert(N <= 8, "vmcnt");
}
static __device__ __forceinline__ void raw_barrier() {
    asm volatile("s_barrier" ::: "memory");
}

// ---------------------------------------------------------------------------
// K_prep: z=0: Wk -> WTk [N][K] bf16; z=1: Wq -> WTq; z=2: wv_sum[i]=sum Wv[i][:]
// ---------------------------------------------------------------------------
__global__ __launch_bounds__(256) void k_prep(const float* __restrict__ Wk,
                                              const float* __restrict__ Wq,
                                              const float* __restrict__ Wv,
                                              ushort* __restrict__ WTk,
                                              ushort* __restrict__ WTq,
                                              float* __restrict__ wv_sum) {
    const int tid = threadIdx.x;
    if (blockIdx.z == 2) {
        __shared__ float red[4];
        const int i = blockIdx.y * 32 + blockIdx.x;
        const float* row = Wv + (size_t)i * D_DIM;
        float p = 0.f;
        for (int c = tid; c < D_DIM; c += 256) p += row[c];
        for (int o = 32; o; o >>= 1) p += __shfl_down(p, o);
        if ((tid & 63) == 0) red[tid >> 6] = p;
        __syncthreads();
        if (tid == 0) wv_sum[i] = red[0] + red[1] + red[2] + red[3];
        return;
    }
    const float* W = (blockIdx.z == 0) ? Wk : Wq;
    ushort* WT     = (blockIdx.z == 0) ? WTk : WTq;
    __shared__ float tile[32][33];          // [k][n]
    const int tx = tid & 31, ty = tid >> 5; // 32 x 8
    const int kb = blockIdx.x * 32, nb = blockIdx.y * 32;
    #pragma unroll
    for (int r = 0; r < 4; ++r)
        tile[ty + 8 * r][tx] = W[(size_t)(kb + ty + 8 * r) * 1024 + nb + tx];
    __syncthreads();
    #pragma unroll
    for (int r = 0; r < 4; ++r)
        WT[(size_t)(nb + ty + 8 * r) * 1024 + kb + tx] =
            f2bs(tile[tx][ty + 8 * r]);
}

// ---------------------------------------------------------------------------
// K1: per t: vsum[b] = x[b,t,:].wv_sum;  y[t,i] = sum_b x[b,t,i]*vsum[b]
// Emits bf16 ROW-MAJOR: yb [T,D], xb [B*T,D]. Vectorized loads/stores.
// ---------------------------------------------------------------------------
__global__ __launch_bounds__(256) void k_vsum_y(const float* __restrict__ x,
                                                const float* __restrict__ wv_sum,
                                                ushort* __restrict__ yb,
                                                ushort* __restrict__ xb) {
    __shared__ float xs[4][D_DIM];
    __shared__ float red[4][4];   // [wave][b]
    const int t = blockIdx.x;
    const int tid = threadIdx.x;
    const int lane = tid & 63, wv = tid >> 6;

    #pragma unroll
    for (int b = 0; b < 4; ++b) {
        const float4* xr = (const float4*)(x + ((size_t)b * T_DIM + t) * D_DIM);
        *(float4*)&xs[b][tid * 4] = xr[tid];
    }
    __syncthreads();

    #pragma unroll
    for (int b = 0; b < 4; ++b) {
        float p = 0.f;
        for (int c = tid; c < D_DIM; c += 256) p += xs[b][c] * wv_sum[c];
        for (int o = 32; o; o >>= 1) p += __shfl_down(p, o);
        if (lane == 0) red[wv][b] = p;
    }
    __syncthreads();

    float vs[4];
    #pragma unroll
    for (int b = 0; b < 4; ++b)
        vs[b] = red[0][b] + red[1][b] + red[2][b] + red[3][b];

    if (tid < 128) {                       // y row t: 128 groups of 8
        const int i0 = tid * 8;
        ushortx8 yv;
        #pragma unroll
        for (int j = 0; j < 8; ++j) {
            float a = 0.f;
            #pragma unroll
            for (int b = 0; b < 4; ++b) a += xs[b][i0 + j] * vs[b];
            yv[j] = f2bs(a);
        }
        *(ushortx8*)(yb + (size_t)t * D_DIM + i0) = yv;
    }
    for (int g = tid; g < 512; g += 256) { // xb rows b*T+t
        const int b = g >> 7, i0 = (g & 127) * 8;
        ushortx8 xv;
        #pragma unroll
        for (int j = 0; j < 8; ++j) xv[j] = f2bs(xs[b][i0 + j]);
        *(ushortx8*)(xb + ((size_t)b * T_DIM + t) * D_DIM + i0) = xv;
    }
}

// ---------------------------------------------------------------------------
// K3: bf16 MFMA GEMM, 512 threads = 8 waves (4 m-rows x 2 n-cols),
// wave-tile (MF*16) x (NF*16); block tile BM=64*MF x BN=32*NF. BK=64.
// Double-buffered LDS + COUNTED vmcnt (loads stay in flight across
// barriers, never vmcnt(0) in loop). XOR-swizzled both sides (rule #21).
// EPI=1: out[r,d] = acc * S2[r & 2047][d]  (S2 pre-scrambled, coalesced).
// ---------------------------------------------------------------------------
template <int MF, int NF, int EPI>
__global__ __launch_bounds__(512, 4) void k_gemm(const ushort* __restrict__ A,
                                                 const ushort* __restrict__ BT,
                                                 float* __restrict__ C,
                                                 const float* __restrict__ S2) {
    constexpr int BM = 4 * MF * 16;
    constexpr int BN = 2 * NF * 16;
    constexpr int LOADS = BM / 64 + BN / 64;   // gload_lds per thread per stage
    __shared__ ushort As[2][BM][64];
    __shared__ ushort Bs[2][BN][64];
    const int tid = threadIdx.x;
    const int lane = tid & 63, wid = tid >> 6;   // 8 waves
    const int wr = wid >> 1, wc = wid & 1;       // 4 x 2
    const int rowBase = blockIdx.x * BM;
    const int colBase = blockIdx.y * BN;

    f32x4 acc[MF][NF];
    #pragma unroll
    for (int i = 0; i < MF; ++i)
        #pragma unroll
        for (int j = 0; j < NF; ++j) acc[i][j] = f32x4{0.f, 0.f, 0.f, 0.f};

    auto stage = [&](int buf, int kb) {
        #pragma unroll
        for (int q = 0; q < BM / 64; ++q) {
            const int s = q * 8192 + tid * 16;           // linear LDS byte
            const int r = s >> 7, grp = (s >> 4) & 7;
            const int gcol = kb + (((grp ^ (r & 7)) & 7) << 3);
            __builtin_amdgcn_global_load_lds(
                (const AS1 void*)(A + (size_t)(rowBase + r) * 1024 + gcol),
                (AS3 void*)((AS3 char*)&As[buf][0][0] + s), 16, 0, 0);
        }
        #pragma unroll
        for (int q = 0; q < BN / 64; ++q) {
            const int s = q * 8192 + tid * 16;
            const int r = s >> 7, grp = (s >> 4) & 7;
            const int gcol = kb + (((grp ^ (r & 7)) & 7) << 3);
            __builtin_amdgcn_global_load_lds(
                (const AS1 void*)(BT + (size_t)(colBase + r) * 1024 + gcol),
                (AS3 void*)((AS3 char*)&Bs[buf][0][0] + s), 16, 0, 0);
        }
    };

    stage(0, 0);                           // waited inside iter 0

    #pragma unroll 2
    for (int kt = 0; kt < 16; ++kt) {
        const int cur = kt & 1;
        if (kt < 15) {
            stage(cur ^ 1, (kt + 1) * 64); // next tile's loads join the queue
            vm_wait<LOADS>();              // wait ONLY for tile kt's loads
        } else {
            vm_wait<0>();
        }
        raw_barrier();                     // buf[cur] valid for all waves

        bf16x8 af[2][MF], bfv[2][NF];
        #pragma unroll
        for (int ks = 0; ks < 2; ++ks) {
            const int kg = ks * 4 + (lane >> 4);
            #pragma unroll
            for (int mi = 0; mi < MF; ++mi) {
                const int r = wr * (MF * 16) + mi * 16 + (lane & 15);
                af[ks][mi] = *(const bf16x8*)((const char*)&As[cur][0][0] +
                                              r * 128 + (((kg ^ (r & 7)) & 7) << 4));
            }
            #pragma unroll
            for (int ni = 0; ni < NF; ++ni) {
                const int r = wc * (NF * 16) + ni * 16 + (lane & 15);
                bfv[ks][ni] = *(const bf16x8*)((const char*)&Bs[cur][0][0] +
                                               r * 128 + (((kg ^ (r & 7)) & 7) << 4));
            }
        }
        #pragma unroll
        for (int ks = 0; ks < 2; ++ks)
            #pragma unroll
            for (int mi = 0; mi < MF; ++mi)
                #pragma unroll
                for (int ni = 0; ni < NF; ++ni)
                    acc[mi][ni] = __builtin_amdgcn_mfma_f32_16x16x32_bf16(
                        af[ks][mi], bfv[ks][ni], acc[mi][ni], 0, 0, 0);

        asm volatile("s_waitcnt lgkmcnt(0)" ::: "memory");
        raw_barrier();                     // reads done; next stage may overwrite
    }

    #pragma unroll
    for (int mi = 0; mi < MF; ++mi) {
        #pragma unroll
        for (int ni = 0; ni < NF; ++ni) {
            const int col = colBase + wc * (NF * 16) + ni * 16 + (lane & 15);
            #pragma unroll
            for (int q = 0; q < 4; ++q) {
                const int row = rowBase + wr * (MF * 16) + mi * 16 + (lane >> 4) * 4 + q;
                float v = acc[mi][ni][q];
                if (EPI)
                    v *= S2[(size_t)(row & (T_DIM - 1)) * D_DIM + col];
                C[(size_t)row * D_DIM + col] = v;
            }
        }
    }
}

// ---------------------------------------------------------------------------
// Parallel scan over t: S[t] = g*S[t-1] + m[t], m[0]:=0, then S[0]=S[1].
// scan2 writes the SCRAMBLED layout: S2[t'][d'] = S[2d'+(t'>>10)][t'&1023],
// i.e. S[t][col] -> S2[(t&1)*1024 + col][t>>1], via an LDS transpose tile
// so both the m-reads and S2-writes are coalesced.
// ---------------------------------------------------------------------------
#define SC_L 32
#define SC_NC 64

__global__ __launch_bounds__(256) void k_scan1(const float* __restrict__ m,
                                               float* __restrict__ tot) {
    const int col = blockIdx.x * 64 + (threadIdx.x & 63);
    const int ch  = blockIdx.y * 4 + (threadIdx.x >> 6);
    const int t0 = ch * SC_L;
    float r = 0.f;
    #pragma unroll 4
    for (int k = 0; k < SC_L; ++k) {
        const int t = t0 + k;
        const float a = (t == 0) ? 0.f : m[(size_t)t * D_DIM + col];
        r = GAMMA_F * r + a;
    }
    tot[(size_t)ch * D_DIM + col] = r;
}

__global__ __launch_bounds__(256) void k_scan2(const float* __restrict__ m,
                                               const float* __restrict__ tot,
                                               float* __restrict__ S2) {
    __shared__ float ls[128][65];
    const int tid = threadIdx.x;
    const int cl = tid & 63;
    const int ch = tid >> 6;              // 0..3 (local chunk)
    const int col = blockIdx.x * 64 + cl;
    const int chg = blockIdx.y * 4 + ch;  // global chunk
    const int t0 = chg * SC_L;

    float gL = 1.f;
    #pragma unroll
    for (int i = 0; i < SC_L; ++i) gL *= GAMMA_F;

    float carry = 0.f, f = 1.f;    // carry = sum_{j<chg} (g^L)^(chg-1-j) tot[j]
    for (int j = chg - 1; j >= 0; --j) {
        carry += f * tot[(size_t)j * D_DIM + col];
        f *= gL;
    }

    float r = carry, s1 = 0.f;
    #pragma unroll 4
    for (int k = 0; k < SC_L; ++k) {
        const int t = t0 + k;
        const float a = (t == 0) ? 0.f : m[(size_t)t * D_DIM + col];
        r = GAMMA_F * r + a;
        ls[ch * SC_L + k][cl] = r;
        if (t == 1) s1 = r;
    }
    if (blockIdx.y == 0 && ch == 0) ls[0][cl] = s1;   // S[0] = S[1]
    __syncthreads();

    // write-out: t = tB + 2j + hi -> S2 row (hi<<10)+c0+cl2, col tB/2 + j
    const int c0 = blockIdx.x * 64;
    const int tB = blockIdx.y * 128;
    for (int e = tid; e < 128 * 64; e += 256) {
        const int rr = e >> 6;            // 0..127
        const int j  = e & 63;
        const int hi = rr >> 6, cl2 = rr & 63;
        S2[(size_t)((hi << 10) + c0 + cl2) * D_DIM + (tB >> 1) + j] =
            ls[2 * j + hi][cl2];
    }
}

// ---------------------------------------------------------------------------
extern "C" void kernel_launch(void* const* d_in, const int* in_sizes, int n_in,
                              void* d_out, int out_size, void* d_ws, size_t ws_size,
                              hipStream_t stream) {
    const float* x  = (const float*)d_in[0];   // [4,2048,1024]
    const float* Wq = (const float*)d_in[1];
    const float* Wk = (const float*)d_in[2];
    const float* Wv = (const float*)d_in[3];
    float* out = (float*)d_out;                // [4,2048,1024] fp32
    char* ws = (char*)d_ws;

    // ws layout (40 MB):
    ushort* xb  = (ushort*)(ws);                    // 16 MB  [B*T,D] bf16
    float*  m   = (float*)(ws + (16u << 20));       //  8 MB  [T,D] fp32
    ushort* yb  = (ushort*)(ws + (24u << 20));      //  4 MB  [T,D] bf16
    ushort* WTk = (ushort*)(ws + (28u << 20));      //  2 MB
    ushort* WTq = (ushort*)(ws + (30u << 20));      //  2 MB
    float*  S2  = (float*)(ws + (32u << 20));       //  8 MB  scrambled S
    float*  wv_sum = m;                 // m row 0: never read by scans
    float*  tot = (float*)yb;           // yb consumed by gemm<0> before scans

    dim3 gP(32, 32, 3);
    k_prep<<<gP, 256, 0, stream>>>(Wk, Wq, Wv, WTk, WTq, wv_sum);

    k_vsum_y<<<T_DIM, 256, 0, stream>>>(x, wv_sum, (ushort*)yb, (ushort*)xb);

    // m = y @ Wk : tile 128x64, grid (16,16) = 256 blocks, 8 waves each
    dim3 gm(T_DIM / 128, D_DIM / 64);
    k_gemm<2, 2, 0><<<gm, 512, 0, stream>>>(yb, WTk, m, nullptr);

    dim3 gs(D_DIM / 64, SC_NC / 4);
    k_scan1<<<gs, 256, 0, stream>>>(m, tot);
    k_scan2<<<gs, 256, 0, stream>>>(m, tot, S2);

    // out = S2 ⊙ (x @ Wq) : tile 128x128, grid (64,8) = 512 blocks, 8 waves
    dim3 gq((4 * T_DIM) / 128, D_DIM / 128);
    k_gemm<2, 4, 1><<<gq, 512, 0, stream>>>(xb, WTq, out, S2);
}